// Round 19
// baseline (122.755 us; speedup 1.0000x reference)
//
#include <hip/hip_runtime.h>

// Problem constants: z_e (16,64,64,64) f32, emb (1024,64) f32
#define NROWS   65536
#define NEMB    1024
#define HWD     4096
#define CHW     262144
#define OUT_ZQ  4194304    // d_out: [0,4194304) z_q_st | [4194304] loss | [4194305,+65536) idx as f32
#define BETA    0.25f
#define MARGIN  4e-3f      // covers dropped z*el (<=2.6e-3 on dist) + rounding wobble
#define MAXC    32

typedef __attribute__((ext_vector_type(8))) short bf16x8;
typedef __attribute__((ext_vector_type(4))) float f32x4;

#define F4C(v,i) ((i)==0?(v).x:((i)==1?(v).y:((i)==2?(v).z:(v).w)))

__device__ __forceinline__ unsigned short bf16rn(float f) {
    unsigned int x = __float_as_uint(f);
    x += 0x7fffu + ((x >> 16) & 1);
    return (unsigned short)(x >> 16);
}
__device__ __forceinline__ float bf16tof(unsigned short h) {
    return __uint_as_float(((unsigned int)h) << 16);
}
__device__ __forceinline__ unsigned int ordf(float f) {
    unsigned int u = __float_as_uint(f);
    return (u & 0x80000000u) ? ~u : (u | 0x80000000u);
}
__device__ __forceinline__ float deordf(unsigned int m) {
    return __uint_as_float((m & 0x80000000u) ? (m ^ 0x80000000u) : ~m);
}

// numpy pairwise_sum for n=64 (bit-exact)
__device__ __forceinline__ float np_pairwise64(const float p[64]) {
#pragma clang fp contract(off)
    float r[8];
#pragma unroll
    for (int a = 0; a < 8; ++a) r[a] = p[a];
#pragma unroll
    for (int i = 8; i < 64; i += 8) {
#pragma unroll
        for (int a = 0; a < 8; ++a) r[a] = r[a] + p[i + a];
    }
    return ((r[0] + r[1]) + (r[2] + r[3])) + ((r[4] + r[5]) + (r[6] + r[7]));
}

__global__ void k_se(const float* __restrict__ emb, float* __restrict__ se) {
#pragma clang fp contract(off)
    int j = blockIdx.x * 256 + threadIdx.x;
    if (j < NEMB) {
        float p[64];
#pragma unroll
        for (int c = 0; c < 64; ++c) { float v = emb[(size_t)j * 64 + c]; p[c] = v * v; }
        se[j] = np_pairwise64(p);
    }
}

// Pack eh = bf16rn(emb) directly in B-fragment order:
// ebt[tile*128 + f*64 + lane] = 8 bf16 for B[k = f*32 + (lane>>4)*8 + i][col = tile*16 + (lane&15)]
__global__ void k_prep(const float* __restrict__ emb, bf16x8* __restrict__ ebt) {
    int idx  = blockIdx.x * 256 + threadIdx.x;   // 0..8191
    int tile = idx >> 7;
    int f    = (idx >> 6) & 1;
    int lane = idx & 63;
    int entry = tile * 16 + (lane & 15);
    int kb    = f * 32 + ((lane >> 4) << 3);
    bf16x8 v;
#pragma unroll
    for (int i = 0; i < 8; ++i)
        v[i] = (short)bf16rn(emb[(size_t)entry * 64 + kb + i]);
    ebt[idx] = v;
}

// MFMA filter (K=128: zh*eh + zl*eh) + exact-f32 re-eval. R16 structure with
// ONE change: zt (16KB LDS copy of the z-tile) deleted - all consumers read
// the identical bits from global ze (L1-resident 16KB tile). Hot loop
// byte-identical. LDS 38400 -> ~22K -> 7 blocks/CU (R16: 4, R15: 3).
__global__ __launch_bounds__(256, 2) void k_mfma(
        const float* __restrict__ ze, const float* __restrict__ emb,
        const bf16x8* __restrict__ ebt, const float* __restrict__ se,
        float* __restrict__ out, float* __restrict__ wsloss) {
#pragma clang fp contract(off)
    __shared__ unsigned short zb[8192];   // [row][zh|zl] bf16 swizzled, 16 KB; upper 8KB reused as cand_s
    __shared__ float se_s[NEMB];
    __shared__ float sz_s[64];
    __shared__ unsigned int rowmin_u[64];
    __shared__ int cnt_s[64];
    __shared__ unsigned long long best_s[64];
    __shared__ int bi_s[64];
    int* cand_s = (int*)&zb[4096];        // byte offset 8K, 64*MAXC*4 = 8 KB

    const int tid  = threadIdx.x;
    const int wid  = tid >> 6;
    const int lane = tid & 63;
    const int l15  = lane & 15;
    const int kg   = lane >> 4;
    const int row0 = blockIdx.x * 64;
    const int b    = row0 >> 12;
    const int hw0  = row0 & 4095;
    const float* __restrict__ zblk = ze + (size_t)b * CHW + hw0;

#pragma unroll
    for (int k = 0; k < 4; ++k) se_s[k * 256 + tid] = se[k * 256 + tid];
    if (tid < 64) { rowmin_u[tid] = 0xFFFFFFFFu; cnt_s[tid] = 0; best_s[tid] = ~0ULL; }
    __syncthreads();

    if (tid < 64) {   // sz, numpy pairwise (bit-exact; zblk[c*HWD+r] == old zt[c*64+r])
        float p[64];
#pragma unroll
        for (int c = 0; c < 64; ++c) { float v = zblk[(size_t)c * HWD + tid]; p[c] = v * v; }
        sz_s[tid] = np_pairwise64(p);
    }

    // build zb from global (same values as old zt path): [row][zh|zl], XOR-swizzled
#pragma unroll
    for (int k4 = 0; k4 < 4; ++k4) {
        int cid = k4 * 256 + tid;
        int row = cid >> 4, kc = cid & 15;
        bf16x8 v;
#pragma unroll
        for (int i = 0; i < 8; ++i) {
            int k = kc * 8 + i;
            float z = zblk[(size_t)(k & 63) * HWD + row];
            unsigned short h = bf16rn(z);
            v[i] = (short)((k < 64) ? h : bf16rn(z - bf16tof(h)));
        }
        *(bf16x8*)&zb[(row * 128 + kc * 8) ^ ((row & 7) << 3)] = v;
    }
    __syncthreads();

    // A-frags for this wave's 16 rows: 4 x bf16x8 = 16 VGPR  (zb dead after this)
    const int arow  = wid * 16 + l15;
    const int abase = arow * 128 + kg * 8;
    const int aswz  = (arow & 7) << 3;
    const bf16x8 Ah0 = *(const bf16x8*)&zb[(abase +  0) ^ aswz];
    const bf16x8 Ah1 = *(const bf16x8*)&zb[(abase + 32) ^ aswz];
    const bf16x8 Al0 = *(const bf16x8*)&zb[(abase + 64) ^ aswz];
    const bf16x8 Al1 = *(const bf16x8*)&zb[(abase + 96) ^ aswz];
    __syncthreads();   // all A-frags read before cand_s (aliased) is written

    float rmin[4] = {3.4028235e38f, 3.4028235e38f, 3.4028235e38f, 3.4028235e38f};
    const bf16x8* __restrict__ ebt_l = ebt + lane;
    const f32x4 zero4 = {0.0f, 0.0f, 0.0f, 0.0f};
    bf16x8 Ca, Cb, Na, Nb;

#define LOADB(T, Xa, Xb) do {                                               \
        const bf16x8* p_ = ebt_l + (T) * 128;                               \
        Xa = p_[0]; Xb = p_[64];                                            \
    } while (0)

#define PROCESS(T, Xa, Xb, PASS2) do {                                      \
        f32x4 acc_ = zero4;                                                 \
        acc_ = __builtin_amdgcn_mfma_f32_16x16x32_bf16(Ah0, Xa, acc_, 0,0,0);\
        acc_ = __builtin_amdgcn_mfma_f32_16x16x32_bf16(Ah1, Xb, acc_, 0,0,0);\
        acc_ = __builtin_amdgcn_mfma_f32_16x16x32_bf16(Al0, Xa, acc_, 0,0,0);\
        acc_ = __builtin_amdgcn_mfma_f32_16x16x32_bf16(Al1, Xb, acc_, 0,0,0);\
        const int j_ = (T) * 16 + l15;                                      \
        const float sej_ = se_s[j_];                                        \
        _Pragma("unroll")                                                   \
        for (int q = 0; q < 4; ++q) {                                       \
            float g_ = fmaf(-2.0f, F4C(acc_, q), sej_);                     \
            if (!(PASS2)) {                                                 \
                rmin[q] = fminf(rmin[q], g_);                               \
            } else if (g_ <= rmin[q]) {                                     \
                int row_ = wid * 16 + kg * 4 + q;                           \
                int k_ = atomicAdd(&cnt_s[row_], 1);                        \
                if (k_ < MAXC) cand_s[row_ * MAXC + k_] = j_;               \
            }                                                               \
        }                                                                   \
    } while (0)

    // ---- pass 1: per-thread min over its j-classes ----
    LOADB(0, Ca, Cb);
    for (int t = 0; t < 64; t += 2) {
        LOADB(t + 1, Na, Nb);
        PROCESS(t, Ca, Cb, false);
        LOADB((t + 2 > 63 ? 63 : t + 2), Ca, Cb);
        PROCESS(t + 1, Na, Nb, false);
    }
#pragma unroll
    for (int q = 0; q < 4; ++q)
        atomicMin(&rowmin_u[wid * 16 + kg * 4 + q], ordf(rmin[q]));
    __syncthreads();
#pragma unroll
    for (int q = 0; q < 4; ++q)
        rmin[q] = deordf(rowmin_u[wid * 16 + kg * 4 + q]) + MARGIN;

    // ---- pass 2: collect candidates within margin ----
    LOADB(0, Ca, Cb);
    for (int t = 0; t < 64; t += 2) {
        LOADB(t + 1, Na, Nb);
        PROCESS(t, Ca, Cb, true);
        LOADB((t + 2 > 63 ? 63 : t + 2), Ca, Cb);
        PROCESS(t + 1, Na, Nb, true);
    }
    __syncthreads();

    // ---- exact re-eval (bit-identical to rounds 1-5 chain; z from global) ----
    for (int w = tid; w < 64 * MAXC; w += 256) {
        int r = w >> 5, ci = w & (MAXC - 1);
        int nc = cnt_s[r];
        if (ci < (nc < MAXC ? nc : MAXC)) {
            int j = cand_s[r * MAXC + ci];
            const float* __restrict__ e = emb + (size_t)j * 64;
            float dot = 0.0f;
#pragma unroll
            for (int c = 0; c < 64; ++c) dot = fmaf(e[c], zblk[(size_t)c * HWD + r], dot);
            float d = (sz_s[r] - 2.0f * dot) + se_s[j];
            atomicMin(&best_s[r],
                      ((unsigned long long)ordf(d) << 32) | (unsigned int)j);
        }
        if (nc > MAXC) {   // statistical never; parallel correctness net
            for (int j = ci; j < NEMB; j += MAXC) {
                const float* __restrict__ e = emb + (size_t)j * 64;
                float dot = 0.0f;
#pragma unroll
                for (int c = 0; c < 64; ++c) dot = fmaf(e[c], zblk[(size_t)c * HWD + r], dot);
                float d = (sz_s[r] - 2.0f * dot) + se_s[j];
                atomicMin(&best_s[r],
                          ((unsigned long long)ordf(d) << 32) | (unsigned int)j);
            }
        }
    }
    __syncthreads();

    if (tid < 64) {
        int j = (int)(best_s[tid] & 0xFFFFFFFFu);
        bi_s[tid] = j;
        out[(size_t)OUT_ZQ + 1 + row0 + tid] = (float)j;
    }
    __syncthreads();

    // z_q_st + loss partial (verbatim round 5)
    float part = 0.0f;
#pragma unroll
    for (int rep = 0; rep < 16; ++rep) {
        int i = rep * 256 + tid;
        int c = i >> 6, r = i & 63;
        int bj = bi_s[r];
        size_t zoff = (size_t)b * CHW + (size_t)c * HWD + hw0 + r;
        float ev = emb[(size_t)bj * 64 + c];
        float zv = ze[zoff];
        float qmz = ev - zv;
        out[zoff] = zv + qmz;
        part = part + qmz * qmz;
    }
    float* red_s = (float*)zb;    // zb bytes 0-1023; no overlap with cand_s region
    red_s[tid] = part;
    __syncthreads();
#pragma unroll
    for (int s = 128; s >= 1; s >>= 1) {
        if (tid < s) red_s[tid] = red_s[tid] + red_s[tid + s];
        __syncthreads();
    }
    if (tid == 0) wsloss[blockIdx.x] = red_s[0];
#undef LOADB
#undef PROCESS
}

// ---------------- round-5 fallback (proven, used if ws too small) ----------
__global__ __launch_bounds__(256, 4) void k_main_v5(
        const float* __restrict__ ze, const float* __restrict__ emb,
        const float* __restrict__ se, float* __restrict__ out,
        float* __restrict__ wsloss) {
#pragma clang fp contract(off)
    __shared__ float zt[4096];
    __shared__ float es[4096];
    __shared__ float se_s[NEMB];
    __shared__ float sz_s[64];
    __shared__ int   bi_s[64];

    const int tid  = threadIdx.x;
    const int rg   = tid & 15;
    const int eg   = tid >> 4;
    const int row0 = blockIdx.x * 64;
    const int b    = row0 >> 12;
    const int hw0  = row0 & 4095;
    const float* __restrict__ zblk = ze + (size_t)b * CHW + hw0;

#pragma unroll
    for (int k = 0; k < 4; ++k) se_s[k * 256 + tid] = se[k * 256 + tid];
#pragma unroll
    for (int k = 0; k < 16; ++k) {
        int idx = k * 256 + tid;
        zt[idx] = zblk[(size_t)(idx >> 6) * HWD + (idx & 63)];
    }
    __syncthreads();
    if (tid < 64) {
        float p[64];
#pragma unroll
        for (int c = 0; c < 64; ++c) { float v = zt[c * 64 + tid]; p[c] = v * v; }
        sz_s[tid] = np_pairwise64(p);
    }
    __syncthreads();
    const float4 sz4 = *(const float4*)&sz_s[rg * 4];
    float best[4] = {3.4028235e38f, 3.4028235e38f, 3.4028235e38f, 3.4028235e38f};
    int   bi[4]   = {0, 0, 0, 0};
    for (int ch = 0; ch < 16; ++ch) {
        __syncthreads();
        {
            const float4* __restrict__ src = (const float4*)(emb + ch * 4096);
#pragma unroll
            for (int k = 0; k < 4; ++k) {
                int idx = k * 256 + tid;
                int jl = idx >> 4, c4 = idx & 15;
                *(float4*)&es[(jl << 6) + ((c4 ^ (jl & 15)) << 2)] = src[idx];
            }
        }
        __syncthreads();
        const float4 se4 = *(const float4*)&se_s[ch * 64 + eg * 4];
        float acc[4][4];
#pragma unroll
        for (int a = 0; a < 4; ++a)
#pragma unroll
            for (int q = 0; q < 4; ++q) acc[a][q] = 0.0f;
#pragma unroll 4
        for (int c4 = 0; c4 < 16; ++c4) {
            float4 zq[4], ef[4];
#pragma unroll
            for (int cc = 0; cc < 4; ++cc)
                zq[cc] = *(const float4*)&zt[((c4 * 4 + cc) << 6) + (rg << 2)];
#pragma unroll
            for (int jj = 0; jj < 4; ++jj) {
                int jl = eg * 4 + jj;
                ef[jj] = *(const float4*)&es[(jl << 6) + ((c4 ^ (jl & 15)) << 2)];
            }
#pragma unroll
            for (int cc = 0; cc < 4; ++cc)
#pragma unroll
                for (int jj = 0; jj < 4; ++jj)
#pragma unroll
                    for (int rr = 0; rr < 4; ++rr)
                        acc[jj][rr] = fmaf(F4C(ef[jj], cc), F4C(zq[cc], rr), acc[jj][rr]);
        }
        const int j0 = ch * 64 + eg * 4;
#pragma unroll
        for (int jj = 0; jj < 4; ++jj) {
            float sej = F4C(se4, jj);
#pragma unroll
            for (int rr = 0; rr < 4; ++rr) {
                float dist = (F4C(sz4, rr) - 2.0f * acc[jj][rr]) + sej;
                if (dist < best[rr]) { best[rr] = dist; bi[rr] = j0 + jj; }
            }
        }
    }
    __syncthreads();
    float* dmin_s = zt;
    int*   imin_s = (int*)es;
#pragma unroll
    for (int rr = 0; rr < 4; ++rr) {
        dmin_s[tid * 4 + rr] = best[rr];
        imin_s[tid * 4 + rr] = bi[rr];
    }
    __syncthreads();
    if (tid < 64) {
        int rgm = tid >> 2, rrm = tid & 3;
        float bb = 3.4028235e38f; int ii = 0x7fffffff;
#pragma unroll
        for (int m = 0; m < 16; ++m) {
            int t = m * 16 + rgm;
            float d  = dmin_s[t * 4 + rrm];
            int   i2 = imin_s[t * 4 + rrm];
            if (d < bb || (d == bb && i2 < ii)) { bb = d; ii = i2; }
        }
        bi_s[tid] = ii;
        out[(size_t)OUT_ZQ + 1 + row0 + tid] = (float)ii;
    }
    __syncthreads();
    float part = 0.0f;
#pragma unroll
    for (int rep = 0; rep < 16; ++rep) {
        int i = rep * 256 + tid;
        int c = i >> 6, r = i & 63;
        int bj = bi_s[r];
        size_t zoff = (size_t)b * CHW + (size_t)c * HWD + hw0 + r;
        float ev = emb[(size_t)bj * 64 + c];
        float zv = ze[zoff];
        float qmz = ev - zv;
        out[zoff] = zv + qmz;
        part = part + qmz * qmz;
    }
    float* red_s = zt;
    red_s[tid] = part;
    __syncthreads();
#pragma unroll
    for (int s = 128; s >= 1; s >>= 1) {
        if (tid < s) red_s[tid] = red_s[tid] + red_s[tid + s];
        __syncthreads();
    }
    if (tid == 0) wsloss[blockIdx.x] = red_s[0];
}

__global__ void k_loss(const float* __restrict__ wsloss, float* __restrict__ out) {
#pragma clang fp contract(off)
    __shared__ float red[256];
    int tid = threadIdx.x;
    float s = 0.0f;
    for (int i = tid; i < 1024; i += 256) s = s + wsloss[i];
    red[tid] = s;
    __syncthreads();
#pragma unroll
    for (int k = 128; k >= 1; k >>= 1) {
        if (tid < k) red[tid] = red[tid] + red[tid + k];
        __syncthreads();
    }
    if (tid == 0) {
        float mse = red[0] / 4194304.0f;
        out[OUT_ZQ] = mse + BETA * mse;
    }
}

extern "C" void kernel_launch(void* const* d_in, const int* in_sizes, int n_in,
                              void* d_out, int out_size, void* d_ws, size_t ws_size,
                              hipStream_t stream) {
    const float* ze  = (const float*)d_in[0];
    const float* emb = (const float*)d_in[1];
    float* out    = (float*)d_out;
    float* se     = (float*)d_ws;
    float* wsloss = se + NEMB;
    bf16x8* ebt   = (bf16x8*)(wsloss + 1024);
    const size_t NEED = 2048 * sizeof(float) + 8192 * sizeof(bf16x8);

    k_se<<<4, 256, 0, stream>>>(emb, se);
    if (ws_size >= NEED) {
        k_prep<<<32,   256, 0, stream>>>(emb, ebt);
        k_mfma<<<1024, 256, 0, stream>>>(ze, emb, ebt, se, out, wsloss);
    } else {
        k_main_v5<<<1024, 256, 0, stream>>>(ze, emb, se, out, wsloss);
    }
    k_loss<<<1, 256, 0, stream>>>(wsloss, out);
}

// Round 20
// 107.554 us; speedup vs baseline: 1.1413x; 1.1413x over previous
//
#include <hip/hip_runtime.h>

// Problem constants: z_e (16,64,64,64) f32, emb (1024,64) f32
#define NROWS   65536
#define NEMB    1024
#define HWD     4096
#define CHW     262144
#define OUT_ZQ  4194304    // d_out: [0,4194304) z_q_st | [4194304] loss | [4194305,+65536) idx as f32
#define BETA    0.25f
#define MARGIN  4e-3f      // covers dropped z*el (<=2.6e-3 on dist) + rounding wobble
#define MAXC    32

typedef __attribute__((ext_vector_type(8))) short bf16x8;
typedef __attribute__((ext_vector_type(4))) float f32x4;

#define F4C(v,i) ((i)==0?(v).x:((i)==1?(v).y:((i)==2?(v).z:(v).w)))

__device__ __forceinline__ unsigned short bf16rn(float f) {
    unsigned int x = __float_as_uint(f);
    x += 0x7fffu + ((x >> 16) & 1);
    return (unsigned short)(x >> 16);
}
__device__ __forceinline__ float bf16tof(unsigned short h) {
    return __uint_as_float(((unsigned int)h) << 16);
}
__device__ __forceinline__ unsigned int ordf(float f) {
    unsigned int u = __float_as_uint(f);
    return (u & 0x80000000u) ? ~u : (u | 0x80000000u);
}
__device__ __forceinline__ float deordf(unsigned int m) {
    return __uint_as_float((m & 0x80000000u) ? (m ^ 0x80000000u) : ~m);
}

// numpy pairwise_sum for n=64 (bit-exact)
__device__ __forceinline__ float np_pairwise64(const float p[64]) {
#pragma clang fp contract(off)
    float r[8];
#pragma unroll
    for (int a = 0; a < 8; ++a) r[a] = p[a];
#pragma unroll
    for (int i = 8; i < 64; i += 8) {
#pragma unroll
        for (int a = 0; a < 8; ++a) r[a] = r[a] + p[i + a];
    }
    return ((r[0] + r[1]) + (r[2] + r[3])) + ((r[4] + r[5]) + (r[6] + r[7]));
}

__global__ void k_se(const float* __restrict__ emb, float* __restrict__ se) {
#pragma clang fp contract(off)
    int j = blockIdx.x * 256 + threadIdx.x;
    if (j < NEMB) {
        float p[64];
#pragma unroll
        for (int c = 0; c < 64; ++c) { float v = emb[(size_t)j * 64 + c]; p[c] = v * v; }
        se[j] = np_pairwise64(p);
    }
}

// Pack eh = bf16rn(emb) directly in B-fragment order:
// ebt[tile*128 + f*64 + lane] = 8 bf16 for B[k = f*32 + (lane>>4)*8 + i][col = tile*16 + (lane&15)]
__global__ void k_prep(const float* __restrict__ emb, bf16x8* __restrict__ ebt) {
    int idx  = blockIdx.x * 256 + threadIdx.x;   // 0..8191
    int tile = idx >> 7;
    int f    = (idx >> 6) & 1;
    int lane = idx & 63;
    int entry = tile * 16 + (lane & 15);
    int kb    = f * 32 + ((lane >> 4) << 3);
    bf16x8 v;
#pragma unroll
    for (int i = 0; i < 8; ++i)
        v[i] = (short)bf16rn(emb[(size_t)entry * 64 + kb + i]);
    ebt[idx] = v;
}

// MFMA filter (K=128: zh*eh + zl*eh) + exact-f32 re-eval. R15 structure with
// ONE change: cand_s aliased onto zb's upper half (zb dead after A-frag loads;
// cand used only after) -> LDS 46592->38400 -> 4 blocks/CU (was 3). Hot loop
// byte-identical to R9/R15's proven codegen. CHAMPION: 107.6 us (R16).
__global__ __launch_bounds__(256, 2) void k_mfma(
        const float* __restrict__ ze, const float* __restrict__ emb,
        const bf16x8* __restrict__ ebt, const float* __restrict__ se,
        float* __restrict__ out, float* __restrict__ wsloss) {
#pragma clang fp contract(off)
    __shared__ float zt[4096];            // z transposed [c][row], 16 KB
    __shared__ unsigned short zb[8192];   // [row][zh|zl] bf16 swizzled, 16 KB; upper 8KB reused as cand_s
    __shared__ float se_s[NEMB];
    __shared__ float sz_s[64];
    __shared__ unsigned int rowmin_u[64];
    __shared__ int cnt_s[64];
    __shared__ unsigned long long best_s[64];
    __shared__ int bi_s[64];
    int* cand_s = (int*)&zb[4096];        // byte offset 8K, 64*MAXC*4 = 8 KB

    const int tid  = threadIdx.x;
    const int wid  = tid >> 6;
    const int lane = tid & 63;
    const int l15  = lane & 15;
    const int kg   = lane >> 4;
    const int row0 = blockIdx.x * 64;
    const int b    = row0 >> 12;
    const int hw0  = row0 & 4095;
    const float* __restrict__ zblk = ze + (size_t)b * CHW + hw0;

#pragma unroll
    for (int k = 0; k < 4; ++k) se_s[k * 256 + tid] = se[k * 256 + tid];
#pragma unroll
    for (int k = 0; k < 16; ++k) {
        int idx = k * 256 + tid;
        zt[idx] = zblk[(size_t)(idx >> 6) * HWD + (idx & 63)];
    }
    if (tid < 64) { rowmin_u[tid] = 0xFFFFFFFFu; cnt_s[tid] = 0; best_s[tid] = ~0ULL; }
    __syncthreads();

    if (tid < 64) {   // sz, numpy pairwise (bit-exact, matches rounds 1-5)
        float p[64];
#pragma unroll
        for (int c = 0; c < 64; ++c) { float v = zt[c * 64 + tid]; p[c] = v * v; }
        sz_s[tid] = np_pairwise64(p);
    }

    // build zb (verbatim R9): [row][zh|zl], XOR-swizzled 8-short granules
#pragma unroll
    for (int k4 = 0; k4 < 4; ++k4) {
        int cid = k4 * 256 + tid;
        int row = cid >> 4, kc = cid & 15;
        bf16x8 v;
#pragma unroll
        for (int i = 0; i < 8; ++i) {
            int k = kc * 8 + i;
            float z = zt[(k & 63) * 64 + row];
            unsigned short h = bf16rn(z);
            v[i] = (short)((k < 64) ? h : bf16rn(z - bf16tof(h)));
        }
        *(bf16x8*)&zb[(row * 128 + kc * 8) ^ ((row & 7) << 3)] = v;
    }
    __syncthreads();

    // A-frags for this wave's 16 rows: 4 x bf16x8 = 16 VGPR  (zb dead after this)
    const int arow  = wid * 16 + l15;
    const int abase = arow * 128 + kg * 8;
    const int aswz  = (arow & 7) << 3;
    const bf16x8 Ah0 = *(const bf16x8*)&zb[(abase +  0) ^ aswz];
    const bf16x8 Ah1 = *(const bf16x8*)&zb[(abase + 32) ^ aswz];
    const bf16x8 Al0 = *(const bf16x8*)&zb[(abase + 64) ^ aswz];
    const bf16x8 Al1 = *(const bf16x8*)&zb[(abase + 96) ^ aswz];
    __syncthreads();   // all A-frags read before cand_s (aliased) is written

    float rmin[4] = {3.4028235e38f, 3.4028235e38f, 3.4028235e38f, 3.4028235e38f};
    const bf16x8* __restrict__ ebt_l = ebt + lane;
    const f32x4 zero4 = {0.0f, 0.0f, 0.0f, 0.0f};
    bf16x8 Ca, Cb, Na, Nb;

#define LOADB(T, Xa, Xb) do {                                               \
        const bf16x8* p_ = ebt_l + (T) * 128;                               \
        Xa = p_[0]; Xb = p_[64];                                            \
    } while (0)

#define PROCESS(T, Xa, Xb, PASS2) do {                                      \
        f32x4 acc_ = zero4;                                                 \
        acc_ = __builtin_amdgcn_mfma_f32_16x16x32_bf16(Ah0, Xa, acc_, 0,0,0);\
        acc_ = __builtin_amdgcn_mfma_f32_16x16x32_bf16(Ah1, Xb, acc_, 0,0,0);\
        acc_ = __builtin_amdgcn_mfma_f32_16x16x32_bf16(Al0, Xa, acc_, 0,0,0);\
        acc_ = __builtin_amdgcn_mfma_f32_16x16x32_bf16(Al1, Xb, acc_, 0,0,0);\
        const int j_ = (T) * 16 + l15;                                      \
        const float sej_ = se_s[j_];                                        \
        _Pragma("unroll")                                                   \
        for (int q = 0; q < 4; ++q) {                                       \
            float g_ = fmaf(-2.0f, F4C(acc_, q), sej_);                     \
            if (!(PASS2)) {                                                 \
                rmin[q] = fminf(rmin[q], g_);                               \
            } else if (g_ <= rmin[q]) {                                     \
                int row_ = wid * 16 + kg * 4 + q;                           \
                int k_ = atomicAdd(&cnt_s[row_], 1);                        \
                if (k_ < MAXC) cand_s[row_ * MAXC + k_] = j_;               \
            }                                                               \
        }                                                                   \
    } while (0)

    // ---- pass 1: per-thread min over its j-classes ----
    LOADB(0, Ca, Cb);
    for (int t = 0; t < 64; t += 2) {
        LOADB(t + 1, Na, Nb);
        PROCESS(t, Ca, Cb, false);
        LOADB((t + 2 > 63 ? 63 : t + 2), Ca, Cb);
        PROCESS(t + 1, Na, Nb, false);
    }
#pragma unroll
    for (int q = 0; q < 4; ++q)
        atomicMin(&rowmin_u[wid * 16 + kg * 4 + q], ordf(rmin[q]));
    __syncthreads();
#pragma unroll
    for (int q = 0; q < 4; ++q)
        rmin[q] = deordf(rowmin_u[wid * 16 + kg * 4 + q]) + MARGIN;

    // ---- pass 2: collect candidates within margin ----
    LOADB(0, Ca, Cb);
    for (int t = 0; t < 64; t += 2) {
        LOADB(t + 1, Na, Nb);
        PROCESS(t, Ca, Cb, true);
        LOADB((t + 2 > 63 ? 63 : t + 2), Ca, Cb);
        PROCESS(t + 1, Na, Nb, true);
    }
    __syncthreads();

    // ---- exact re-eval (bit-identical to rounds 1-5 chain) ----
    for (int w = tid; w < 64 * MAXC; w += 256) {
        int r = w >> 5, ci = w & (MAXC - 1);
        int nc = cnt_s[r];
        if (ci < (nc < MAXC ? nc : MAXC)) {
            int j = cand_s[r * MAXC + ci];
            const float* __restrict__ e = emb + (size_t)j * 64;
            float dot = 0.0f;
#pragma unroll
            for (int c = 0; c < 64; ++c) dot = fmaf(e[c], zt[c * 64 + r], dot);
            float d = (sz_s[r] - 2.0f * dot) + se_s[j];
            atomicMin(&best_s[r],
                      ((unsigned long long)ordf(d) << 32) | (unsigned int)j);
        }
        if (nc > MAXC) {   // statistical never; parallel correctness net
            for (int j = ci; j < NEMB; j += MAXC) {
                const float* __restrict__ e = emb + (size_t)j * 64;
                float dot = 0.0f;
#pragma unroll
                for (int c = 0; c < 64; ++c) dot = fmaf(e[c], zt[c * 64 + r], dot);
                float d = (sz_s[r] - 2.0f * dot) + se_s[j];
                atomicMin(&best_s[r],
                          ((unsigned long long)ordf(d) << 32) | (unsigned int)j);
            }
        }
    }
    __syncthreads();

    if (tid < 64) {
        int j = (int)(best_s[tid] & 0xFFFFFFFFu);
        bi_s[tid] = j;
        out[(size_t)OUT_ZQ + 1 + row0 + tid] = (float)j;
    }
    __syncthreads();

    // z_q_st + loss partial (verbatim round 5)
    float part = 0.0f;
#pragma unroll
    for (int rep = 0; rep < 16; ++rep) {
        int i = rep * 256 + tid;
        int c = i >> 6, r = i & 63;
        int bj = bi_s[r];
        size_t zoff = (size_t)b * CHW + (size_t)c * HWD + hw0 + r;
        float ev = emb[(size_t)bj * 64 + c];
        float zv = ze[zoff];
        float qmz = ev - zv;
        out[zoff] = zv + qmz;
        part = part + qmz * qmz;
    }
    float* red_s = (float*)zb;    // zb bytes 0-1023; no overlap with cand_s region
    red_s[tid] = part;
    __syncthreads();
#pragma unroll
    for (int s = 128; s >= 1; s >>= 1) {
        if (tid < s) red_s[tid] = red_s[tid] + red_s[tid + s];
        __syncthreads();
    }
    if (tid == 0) wsloss[blockIdx.x] = red_s[0];
#undef LOADB
#undef PROCESS
}

// ---------------- round-5 fallback (proven, used if ws too small) ----------
__global__ __launch_bounds__(256, 4) void k_main_v5(
        const float* __restrict__ ze, const float* __restrict__ emb,
        const float* __restrict__ se, float* __restrict__ out,
        float* __restrict__ wsloss) {
#pragma clang fp contract(off)
    __shared__ float zt[4096];
    __shared__ float es[4096];
    __shared__ float se_s[NEMB];
    __shared__ float sz_s[64];
    __shared__ int   bi_s[64];

    const int tid  = threadIdx.x;
    const int rg   = tid & 15;
    const int eg   = tid >> 4;
    const int row0 = blockIdx.x * 64;
    const int b    = row0 >> 12;
    const int hw0  = row0 & 4095;
    const float* __restrict__ zblk = ze + (size_t)b * CHW + hw0;

#pragma unroll
    for (int k = 0; k < 4; ++k) se_s[k * 256 + tid] = se[k * 256 + tid];
#pragma unroll
    for (int k = 0; k < 16; ++k) {
        int idx = k * 256 + tid;
        zt[idx] = zblk[(size_t)(idx >> 6) * HWD + (idx & 63)];
    }
    __syncthreads();
    if (tid < 64) {
        float p[64];
#pragma unroll
        for (int c = 0; c < 64; ++c) { float v = zt[c * 64 + tid]; p[c] = v * v; }
        sz_s[tid] = np_pairwise64(p);
    }
    __syncthreads();
    const float4 sz4 = *(const float4*)&sz_s[rg * 4];
    float best[4] = {3.4028235e38f, 3.4028235e38f, 3.4028235e38f, 3.4028235e38f};
    int   bi[4]   = {0, 0, 0, 0};
    for (int ch = 0; ch < 16; ++ch) {
        __syncthreads();
        {
            const float4* __restrict__ src = (const float4*)(emb + ch * 4096);
#pragma unroll
            for (int k = 0; k < 4; ++k) {
                int idx = k * 256 + tid;
                int jl = idx >> 4, c4 = idx & 15;
                *(float4*)&es[(jl << 6) + ((c4 ^ (jl & 15)) << 2)] = src[idx];
            }
        }
        __syncthreads();
        const float4 se4 = *(const float4*)&se_s[ch * 64 + eg * 4];
        float acc[4][4];
#pragma unroll
        for (int a = 0; a < 4; ++a)
#pragma unroll
            for (int q = 0; q < 4; ++q) acc[a][q] = 0.0f;
#pragma unroll 4
        for (int c4 = 0; c4 < 16; ++c4) {
            float4 zq[4], ef[4];
#pragma unroll
            for (int cc = 0; cc < 4; ++cc)
                zq[cc] = *(const float4*)&zt[((c4 * 4 + cc) << 6) + (rg << 2)];
#pragma unroll
            for (int jj = 0; jj < 4; ++jj) {
                int jl = eg * 4 + jj;
                ef[jj] = *(const float4*)&es[(jl << 6) + ((c4 ^ (jl & 15)) << 2)];
            }
#pragma unroll
            for (int cc = 0; cc < 4; ++cc)
#pragma unroll
                for (int jj = 0; jj < 4; ++jj)
#pragma unroll
                    for (int rr = 0; rr < 4; ++rr)
                        acc[jj][rr] = fmaf(F4C(ef[jj], cc), F4C(zq[cc], rr), acc[jj][rr]);
        }
        const int j0 = ch * 64 + eg * 4;
#pragma unroll
        for (int jj = 0; jj < 4; ++jj) {
            float sej = F4C(se4, jj);
#pragma unroll
            for (int rr = 0; rr < 4; ++rr) {
                float dist = (F4C(sz4, rr) - 2.0f * acc[jj][rr]) + sej;
                if (dist < best[rr]) { best[rr] = dist; bi[rr] = j0 + jj; }
            }
        }
    }
    __syncthreads();
    float* dmin_s = zt;
    int*   imin_s = (int*)es;
#pragma unroll
    for (int rr = 0; rr < 4; ++rr) {
        dmin_s[tid * 4 + rr] = best[rr];
        imin_s[tid * 4 + rr] = bi[rr];
    }
    __syncthreads();
    if (tid < 64) {
        int rgm = tid >> 2, rrm = tid & 3;
        float bb = 3.4028235e38f; int ii = 0x7fffffff;
#pragma unroll
        for (int m = 0; m < 16; ++m) {
            int t = m * 16 + rgm;
            float d  = dmin_s[t * 4 + rrm];
            int   i2 = imin_s[t * 4 + rrm];
            if (d < bb || (d == bb && i2 < ii)) { bb = d; ii = i2; }
        }
        bi_s[tid] = ii;
        out[(size_t)OUT_ZQ + 1 + row0 + tid] = (float)ii;
    }
    __syncthreads();
    float part = 0.0f;
#pragma unroll
    for (int rep = 0; rep < 16; ++rep) {
        int i = rep * 256 + tid;
        int c = i >> 6, r = i & 63;
        int bj = bi_s[r];
        size_t zoff = (size_t)b * CHW + (size_t)c * HWD + hw0 + r;
        float ev = emb[(size_t)bj * 64 + c];
        float zv = ze[zoff];
        float qmz = ev - zv;
        out[zoff] = zv + qmz;
        part = part + qmz * qmz;
    }
    float* red_s = zt;
    red_s[tid] = part;
    __syncthreads();
#pragma unroll
    for (int s = 128; s >= 1; s >>= 1) {
        if (tid < s) red_s[tid] = red_s[tid] + red_s[tid + s];
        __syncthreads();
    }
    if (tid == 0) wsloss[blockIdx.x] = red_s[0];
}

__global__ void k_loss(const float* __restrict__ wsloss, float* __restrict__ out) {
#pragma clang fp contract(off)
    __shared__ float red[256];
    int tid = threadIdx.x;
    float s = 0.0f;
    for (int i = tid; i < 1024; i += 256) s = s + wsloss[i];
    red[tid] = s;
    __syncthreads();
#pragma unroll
    for (int k = 128; k >= 1; k >>= 1) {
        if (tid < k) red[tid] = red[tid] + red[tid + k];
        __syncthreads();
    }
    if (tid == 0) {
        float mse = red[0] / 4194304.0f;
        out[OUT_ZQ] = mse + BETA * mse;
    }
}

extern "C" void kernel_launch(void* const* d_in, const int* in_sizes, int n_in,
                              void* d_out, int out_size, void* d_ws, size_t ws_size,
                              hipStream_t stream) {
    const float* ze  = (const float*)d_in[0];
    const float* emb = (const float*)d_in[1];
    float* out    = (float*)d_out;
    float* se     = (float*)d_ws;
    float* wsloss = se + NEMB;
    bf16x8* ebt   = (bf16x8*)(wsloss + 1024);
    const size_t NEED = 2048 * sizeof(float) + 8192 * sizeof(bf16x8);

    k_se<<<4, 256, 0, stream>>>(emb, se);
    if (ws_size >= NEED) {
        k_prep<<<32,   256, 0, stream>>>(emb, ebt);
        k_mfma<<<1024, 256, 0, stream>>>(ze, emb, ebt, se, out, wsloss);
    } else {
        k_main_v5<<<1024, 256, 0, stream>>>(ze, emb, se, out, wsloss);
    }
    k_loss<<<1, 256, 0, stream>>>(wsloss, out);
}

// Round 21
// 105.194 us; speedup vs baseline: 1.1669x; 1.0224x over previous
//
#include <hip/hip_runtime.h>

// Problem constants: z_e (16,64,64,64) f32, emb (1024,64) f32
#define NROWS   65536
#define NEMB    1024
#define HWD     4096
#define CHW     262144
#define OUT_ZQ  4194304    // d_out: [0,4194304) z_q_st | [4194304] loss | [4194305,+65536) idx as f32
#define BETA    0.25f
#define MARGIN  4e-3f      // covers dropped z*el (<=2.6e-3 on dist) + rounding wobble
#define MAXC    32

typedef __attribute__((ext_vector_type(8))) short bf16x8;
typedef __attribute__((ext_vector_type(4))) float f32x4;

#define F4C(v,i) ((i)==0?(v).x:((i)==1?(v).y:((i)==2?(v).z:(v).w)))

__device__ __forceinline__ unsigned short bf16rn(float f) {
    unsigned int x = __float_as_uint(f);
    x += 0x7fffu + ((x >> 16) & 1);
    return (unsigned short)(x >> 16);
}
__device__ __forceinline__ float bf16tof(unsigned short h) {
    return __uint_as_float(((unsigned int)h) << 16);
}
__device__ __forceinline__ unsigned int ordf(float f) {
    unsigned int u = __float_as_uint(f);
    return (u & 0x80000000u) ? ~u : (u | 0x80000000u);
}
__device__ __forceinline__ float deordf(unsigned int m) {
    return __uint_as_float((m & 0x80000000u) ? (m ^ 0x80000000u) : ~m);
}

// numpy pairwise_sum for n=64 (bit-exact)
__device__ __forceinline__ float np_pairwise64(const float p[64]) {
#pragma clang fp contract(off)
    float r[8];
#pragma unroll
    for (int a = 0; a < 8; ++a) r[a] = p[a];
#pragma unroll
    for (int i = 8; i < 64; i += 8) {
#pragma unroll
        for (int a = 0; a < 8; ++a) r[a] = r[a] + p[i + a];
    }
    return ((r[0] + r[1]) + (r[2] + r[3])) + ((r[4] + r[5]) + (r[6] + r[7]));
}

// Merged prep (proven in R10-R14): ebt B-fragment packing (all 32 blocks)
// + se (blocks 0-3).
// ebt[tile*128 + f*64 + lane] = 8 bf16 for B[k=f*32+(lane>>4)*8+i][col=tile*16+(lane&15)]
__global__ void k_prep(const float* __restrict__ emb, bf16x8* __restrict__ ebt,
                       float* __restrict__ se) {
#pragma clang fp contract(off)
    int idx  = blockIdx.x * 256 + threadIdx.x;   // 0..8191
    int tile = idx >> 7;
    int f    = (idx >> 6) & 1;
    int lane = idx & 63;
    int entry = tile * 16 + (lane & 15);
    int kb    = f * 32 + ((lane >> 4) << 3);
    bf16x8 v;
#pragma unroll
    for (int i = 0; i < 8; ++i)
        v[i] = (short)bf16rn(emb[(size_t)entry * 64 + kb + i]);
    ebt[idx] = v;

    if (blockIdx.x < 4) {
        int j = blockIdx.x * 256 + threadIdx.x;
        float p[64];
#pragma unroll
        for (int c = 0; c < 64; ++c) { float vv = emb[(size_t)j * 64 + c]; p[c] = vv * vv; }
        se[j] = np_pairwise64(p);
    }
}

// MFMA filter (K=128: zh*eh + zl*eh) + exact-f32 re-eval. CHAMPION k_mfma
// (R16/R20, 107.55us total, byte-identical here): cand_s aliased onto zb's
// upper half -> LDS 38400 -> 4 blocks/CU; hot loop = R9's proven dbuf codegen.
__global__ __launch_bounds__(256, 2) void k_mfma(
        const float* __restrict__ ze, const float* __restrict__ emb,
        const bf16x8* __restrict__ ebt, const float* __restrict__ se,
        float* __restrict__ out, float* __restrict__ wsloss) {
#pragma clang fp contract(off)
    __shared__ float zt[4096];            // z transposed [c][row], 16 KB
    __shared__ unsigned short zb[8192];   // [row][zh|zl] bf16 swizzled, 16 KB; upper 8KB reused as cand_s
    __shared__ float se_s[NEMB];
    __shared__ float sz_s[64];
    __shared__ unsigned int rowmin_u[64];
    __shared__ int cnt_s[64];
    __shared__ unsigned long long best_s[64];
    __shared__ int bi_s[64];
    int* cand_s = (int*)&zb[4096];        // byte offset 8K, 64*MAXC*4 = 8 KB

    const int tid  = threadIdx.x;
    const int wid  = tid >> 6;
    const int lane = tid & 63;
    const int l15  = lane & 15;
    const int kg   = lane >> 4;
    const int row0 = blockIdx.x * 64;
    const int b    = row0 >> 12;
    const int hw0  = row0 & 4095;
    const float* __restrict__ zblk = ze + (size_t)b * CHW + hw0;

#pragma unroll
    for (int k = 0; k < 4; ++k) se_s[k * 256 + tid] = se[k * 256 + tid];
#pragma unroll
    for (int k = 0; k < 16; ++k) {
        int idx = k * 256 + tid;
        zt[idx] = zblk[(size_t)(idx >> 6) * HWD + (idx & 63)];
    }
    if (tid < 64) { rowmin_u[tid] = 0xFFFFFFFFu; cnt_s[tid] = 0; best_s[tid] = ~0ULL; }
    __syncthreads();

    if (tid < 64) {   // sz, numpy pairwise (bit-exact, matches rounds 1-5)
        float p[64];
#pragma unroll
        for (int c = 0; c < 64; ++c) { float v = zt[c * 64 + tid]; p[c] = v * v; }
        sz_s[tid] = np_pairwise64(p);
    }

    // build zb (verbatim R9): [row][zh|zl], XOR-swizzled 8-short granules
#pragma unroll
    for (int k4 = 0; k4 < 4; ++k4) {
        int cid = k4 * 256 + tid;
        int row = cid >> 4, kc = cid & 15;
        bf16x8 v;
#pragma unroll
        for (int i = 0; i < 8; ++i) {
            int k = kc * 8 + i;
            float z = zt[(k & 63) * 64 + row];
            unsigned short h = bf16rn(z);
            v[i] = (short)((k < 64) ? h : bf16rn(z - bf16tof(h)));
        }
        *(bf16x8*)&zb[(row * 128 + kc * 8) ^ ((row & 7) << 3)] = v;
    }
    __syncthreads();

    // A-frags for this wave's 16 rows: 4 x bf16x8 = 16 VGPR  (zb dead after this)
    const int arow  = wid * 16 + l15;
    const int abase = arow * 128 + kg * 8;
    const int aswz  = (arow & 7) << 3;
    const bf16x8 Ah0 = *(const bf16x8*)&zb[(abase +  0) ^ aswz];
    const bf16x8 Ah1 = *(const bf16x8*)&zb[(abase + 32) ^ aswz];
    const bf16x8 Al0 = *(const bf16x8*)&zb[(abase + 64) ^ aswz];
    const bf16x8 Al1 = *(const bf16x8*)&zb[(abase + 96) ^ aswz];
    __syncthreads();   // all A-frags read before cand_s (aliased) is written

    float rmin[4] = {3.4028235e38f, 3.4028235e38f, 3.4028235e38f, 3.4028235e38f};
    const bf16x8* __restrict__ ebt_l = ebt + lane;
    const f32x4 zero4 = {0.0f, 0.0f, 0.0f, 0.0f};
    bf16x8 Ca, Cb, Na, Nb;

#define LOADB(T, Xa, Xb) do {                                               \
        const bf16x8* p_ = ebt_l + (T) * 128;                               \
        Xa = p_[0]; Xb = p_[64];                                            \
    } while (0)

#define PROCESS(T, Xa, Xb, PASS2) do {                                      \
        f32x4 acc_ = zero4;                                                 \
        acc_ = __builtin_amdgcn_mfma_f32_16x16x32_bf16(Ah0, Xa, acc_, 0,0,0);\
        acc_ = __builtin_amdgcn_mfma_f32_16x16x32_bf16(Ah1, Xb, acc_, 0,0,0);\
        acc_ = __builtin_amdgcn_mfma_f32_16x16x32_bf16(Al0, Xa, acc_, 0,0,0);\
        acc_ = __builtin_amdgcn_mfma_f32_16x16x32_bf16(Al1, Xb, acc_, 0,0,0);\
        const int j_ = (T) * 16 + l15;                                      \
        const float sej_ = se_s[j_];                                        \
        _Pragma("unroll")                                                   \
        for (int q = 0; q < 4; ++q) {                                       \
            float g_ = fmaf(-2.0f, F4C(acc_, q), sej_);                     \
            if (!(PASS2)) {                                                 \
                rmin[q] = fminf(rmin[q], g_);                               \
            } else if (g_ <= rmin[q]) {                                     \
                int row_ = wid * 16 + kg * 4 + q;                           \
                int k_ = atomicAdd(&cnt_s[row_], 1);                        \
                if (k_ < MAXC) cand_s[row_ * MAXC + k_] = j_;               \
            }                                                               \
        }                                                                   \
    } while (0)

    // ---- pass 1: per-thread min over its j-classes ----
    LOADB(0, Ca, Cb);
    for (int t = 0; t < 64; t += 2) {
        LOADB(t + 1, Na, Nb);
        PROCESS(t, Ca, Cb, false);
        LOADB((t + 2 > 63 ? 63 : t + 2), Ca, Cb);
        PROCESS(t + 1, Na, Nb, false);
    }
#pragma unroll
    for (int q = 0; q < 4; ++q)
        atomicMin(&rowmin_u[wid * 16 + kg * 4 + q], ordf(rmin[q]));
    __syncthreads();
#pragma unroll
    for (int q = 0; q < 4; ++q)
        rmin[q] = deordf(rowmin_u[wid * 16 + kg * 4 + q]) + MARGIN;

    // ---- pass 2: collect candidates within margin ----
    LOADB(0, Ca, Cb);
    for (int t = 0; t < 64; t += 2) {
        LOADB(t + 1, Na, Nb);
        PROCESS(t, Ca, Cb, true);
        LOADB((t + 2 > 63 ? 63 : t + 2), Ca, Cb);
        PROCESS(t + 1, Na, Nb, true);
    }
    __syncthreads();

    // ---- exact re-eval (bit-identical to rounds 1-5 chain) ----
    for (int w = tid; w < 64 * MAXC; w += 256) {
        int r = w >> 5, ci = w & (MAXC - 1);
        int nc = cnt_s[r];
        if (ci < (nc < MAXC ? nc : MAXC)) {
            int j = cand_s[r * MAXC + ci];
            const float* __restrict__ e = emb + (size_t)j * 64;
            float dot = 0.0f;
#pragma unroll
            for (int c = 0; c < 64; ++c) dot = fmaf(e[c], zt[c * 64 + r], dot);
            float d = (sz_s[r] - 2.0f * dot) + se_s[j];
            atomicMin(&best_s[r],
                      ((unsigned long long)ordf(d) << 32) | (unsigned int)j);
        }
        if (nc > MAXC) {   // statistical never; parallel correctness net
            for (int j = ci; j < NEMB; j += MAXC) {
                const float* __restrict__ e = emb + (size_t)j * 64;
                float dot = 0.0f;
#pragma unroll
                for (int c = 0; c < 64; ++c) dot = fmaf(e[c], zt[c * 64 + r], dot);
                float d = (sz_s[r] - 2.0f * dot) + se_s[j];
                atomicMin(&best_s[r],
                          ((unsigned long long)ordf(d) << 32) | (unsigned int)j);
            }
        }
    }
    __syncthreads();

    if (tid < 64) {
        int j = (int)(best_s[tid] & 0xFFFFFFFFu);
        bi_s[tid] = j;
        out[(size_t)OUT_ZQ + 1 + row0 + tid] = (float)j;
    }
    __syncthreads();

    // z_q_st + loss partial (verbatim round 5)
    float part = 0.0f;
#pragma unroll
    for (int rep = 0; rep < 16; ++rep) {
        int i = rep * 256 + tid;
        int c = i >> 6, r = i & 63;
        int bj = bi_s[r];
        size_t zoff = (size_t)b * CHW + (size_t)c * HWD + hw0 + r;
        float ev = emb[(size_t)bj * 64 + c];
        float zv = ze[zoff];
        float qmz = ev - zv;
        out[zoff] = zv + qmz;
        part = part + qmz * qmz;
    }
    float* red_s = (float*)zb;    // zb bytes 0-1023; no overlap with cand_s region
    red_s[tid] = part;
    __syncthreads();
#pragma unroll
    for (int s = 128; s >= 1; s >>= 1) {
        if (tid < s) red_s[tid] = red_s[tid] + red_s[tid + s];
        __syncthreads();
    }
    if (tid == 0) wsloss[blockIdx.x] = red_s[0];
#undef LOADB
#undef PROCESS
}

// ---------------- round-5 fallback (proven, used if ws too small) ----------
__global__ __launch_bounds__(256, 4) void k_main_v5(
        const float* __restrict__ ze, const float* __restrict__ emb,
        const float* __restrict__ se, float* __restrict__ out,
        float* __restrict__ wsloss) {
#pragma clang fp contract(off)
    __shared__ float zt[4096];
    __shared__ float es[4096];
    __shared__ float se_s[NEMB];
    __shared__ float sz_s[64];
    __shared__ int   bi_s[64];

    const int tid  = threadIdx.x;
    const int rg   = tid & 15;
    const int eg   = tid >> 4;
    const int row0 = blockIdx.x * 64;
    const int b    = row0 >> 12;
    const int hw0  = row0 & 4095;
    const float* __restrict__ zblk = ze + (size_t)b * CHW + hw0;

#pragma unroll
    for (int k = 0; k < 4; ++k) se_s[k * 256 + tid] = se[k * 256 + tid];
#pragma unroll
    for (int k = 0; k < 16; ++k) {
        int idx = k * 256 + tid;
        zt[idx] = zblk[(size_t)(idx >> 6) * HWD + (idx & 63)];
    }
    __syncthreads();
    if (tid < 64) {
        float p[64];
#pragma unroll
        for (int c = 0; c < 64; ++c) { float v = zt[c * 64 + tid]; p[c] = v * v; }
        sz_s[tid] = np_pairwise64(p);
    }
    __syncthreads();
    const float4 sz4 = *(const float4*)&sz_s[rg * 4];
    float best[4] = {3.4028235e38f, 3.4028235e38f, 3.4028235e38f, 3.4028235e38f};
    int   bi[4]   = {0, 0, 0, 0};
    for (int ch = 0; ch < 16; ++ch) {
        __syncthreads();
        {
            const float4* __restrict__ src = (const float4*)(emb + ch * 4096);
#pragma unroll
            for (int k = 0; k < 4; ++k) {
                int idx = k * 256 + tid;
                int jl = idx >> 4, c4 = idx & 15;
                *(float4*)&es[(jl << 6) + ((c4 ^ (jl & 15)) << 2)] = src[idx];
            }
        }
        __syncthreads();
        const float4 se4 = *(const float4*)&se_s[ch * 64 + eg * 4];
        float acc[4][4];
#pragma unroll
        for (int a = 0; a < 4; ++a)
#pragma unroll
            for (int q = 0; q < 4; ++q) acc[a][q] = 0.0f;
#pragma unroll 4
        for (int c4 = 0; c4 < 16; ++c4) {
            float4 zq[4], ef[4];
#pragma unroll
            for (int cc = 0; cc < 4; ++cc)
                zq[cc] = *(const float4*)&zt[((c4 * 4 + cc) << 6) + (rg << 2)];
#pragma unroll
            for (int jj = 0; jj < 4; ++jj) {
                int jl = eg * 4 + jj;
                ef[jj] = *(const float4*)&es[(jl << 6) + ((c4 ^ (jl & 15)) << 2)];
            }
#pragma unroll
            for (int cc = 0; cc < 4; ++cc)
#pragma unroll
                for (int jj = 0; jj < 4; ++jj)
#pragma unroll
                    for (int rr = 0; rr < 4; ++rr)
                        acc[jj][rr] = fmaf(F4C(ef[jj], cc), F4C(zq[cc], rr), acc[jj][rr]);
        }
        const int j0 = ch * 64 + eg * 4;
#pragma unroll
        for (int jj = 0; jj < 4; ++jj) {
            float sej = F4C(se4, jj);
#pragma unroll
            for (int rr = 0; rr < 4; ++rr) {
                float dist = (F4C(sz4, rr) - 2.0f * acc[jj][rr]) + sej;
                if (dist < best[rr]) { best[rr] = dist; bi[rr] = j0 + jj; }
            }
        }
    }
    __syncthreads();
    float* dmin_s = zt;
    int*   imin_s = (int*)es;
#pragma unroll
    for (int rr = 0; rr < 4; ++rr) {
        dmin_s[tid * 4 + rr] = best[rr];
        imin_s[tid * 4 + rr] = bi[rr];
    }
    __syncthreads();
    if (tid < 64) {
        int rgm = tid >> 2, rrm = tid & 3;
        float bb = 3.4028235e38f; int ii = 0x7fffffff;
#pragma unroll
        for (int m = 0; m < 16; ++m) {
            int t = m * 16 + rgm;
            float d  = dmin_s[t * 4 + rrm];
            int   i2 = imin_s[t * 4 + rrm];
            if (d < bb || (d == bb && i2 < ii)) { bb = d; ii = i2; }
        }
        bi_s[tid] = ii;
        out[(size_t)OUT_ZQ + 1 + row0 + tid] = (float)ii;
    }
    __syncthreads();
    float part = 0.0f;
#pragma unroll
    for (int rep = 0; rep < 16; ++rep) {
        int i = rep * 256 + tid;
        int c = i >> 6, r = i & 63;
        int bj = bi_s[r];
        size_t zoff = (size_t)b * CHW + (size_t)c * HWD + hw0 + r;
        float ev = emb[(size_t)bj * 64 + c];
        float zv = ze[zoff];
        float qmz = ev - zv;
        out[zoff] = zv + qmz;
        part = part + qmz * qmz;
    }
    float* red_s = zt;
    red_s[tid] = part;
    __syncthreads();
#pragma unroll
    for (int s = 128; s >= 1; s >>= 1) {
        if (tid < s) red_s[tid] = red_s[tid] + red_s[tid + s];
        __syncthreads();
    }
    if (tid == 0) wsloss[blockIdx.x] = red_s[0];
}

__global__ void k_loss(const float* __restrict__ wsloss, float* __restrict__ out) {
#pragma clang fp contract(off)
    __shared__ float red[256];
    int tid = threadIdx.x;
    float s = 0.0f;
    for (int i = tid; i < 1024; i += 256) s = s + wsloss[i];
    red[tid] = s;
    __syncthreads();
#pragma unroll
    for (int k = 128; k >= 1; k >>= 1) {
        if (tid < k) red[tid] = red[tid] + red[tid + k];
        __syncthreads();
    }
    if (tid == 0) {
        float mse = red[0] / 4194304.0f;
        out[OUT_ZQ] = mse + BETA * mse;
    }
}

extern "C" void kernel_launch(void* const* d_in, const int* in_sizes, int n_in,
                              void* d_out, int out_size, void* d_ws, size_t ws_size,
                              hipStream_t stream) {
    const float* ze  = (const float*)d_in[0];
    const float* emb = (const float*)d_in[1];
    float* out    = (float*)d_out;
    float* se     = (float*)d_ws;
    float* wsloss = se + NEMB;
    bf16x8* ebt   = (bf16x8*)(wsloss + 1024);
    const size_t NEED = 2048 * sizeof(float) + 8192 * sizeof(bf16x8);

    if (ws_size >= NEED) {
        k_prep<<<32,   256, 0, stream>>>(emb, ebt, se);
        k_mfma<<<1024, 256, 0, stream>>>(ze, emb, ebt, se, out, wsloss);
    } else {
        k_prep<<<32, 256, 0, stream>>>(emb, (bf16x8*)d_ws, se);  // ebt region unused by fallback
        k_main_v5<<<1024, 256, 0, stream>>>(ze, emb, se, out, wsloss);
    }
    k_loss<<<1, 256, 0, stream>>>(wsloss, out);
}